// Round 2
// baseline (555.505 us; speedup 1.0000x reference)
//
#include <hip/hip_runtime.h>

#define NNODES 196608
#define NH 9
#define F 64
#define LN_EPS 1e-5f

__device__ __forceinline__ float silu_f(float z) {
    return z / (1.0f + __expf(-z));
}

// One wave per row: LN over 64 features + SiLU.
__global__ __launch_bounds__(256) void ln1_silu_kernel(
    const float* __restrict__ x, const float* __restrict__ w,
    const float* __restrict__ b, float* __restrict__ out)
{
    int row = blockIdx.x * 4 + (threadIdx.x >> 6);
    int lane = threadIdx.x & 63;
    size_t off = (size_t)row * F + lane;
    float v = x[off];
    float s = v;
#pragma unroll
    for (int o = 32; o; o >>= 1) s += __shfl_xor(s, o);
    float mu = s * (1.0f / F);
    float d = v - mu;
    float q = d * d;
#pragma unroll
    for (int o = 32; o; o >>= 1) q += __shfl_xor(q, o);
    float rstd = rsqrtf(q * (1.0f / F) + LN_EPS);
    float y = d * rstd * w[lane] + b[lane];
    out[off] = silu_f(y);
}

// Thread-per-node gather + 9-head 64x64 matmul. W[k] staged in LDS (16 KB),
// read at wave-uniform addresses (broadcast). 64 f32 accumulators per thread.
// FINAL==0: fused LN2+SiLU epilogue. FINAL==1: +residual epilogue.
template<int FINAL>
__global__ __launch_bounds__(256) void gconv_kernel(
    const float* __restrict__ h, const int* __restrict__ adjc,
    const float* __restrict__ W, const float* __restrict__ bias,
    const float* __restrict__ lnw, const float* __restrict__ lnb,
    const float* __restrict__ xres, float* __restrict__ out)
{
    __shared__ float Wk[F * F];
    const int node = blockIdx.x * 256 + threadIdx.x;
    float acc[F];
#pragma unroll
    for (int o = 0; o < F; ++o) acc[o] = bias[o];

    const int* arow = adjc + (size_t)node * NH;
    for (int k = 0; k < NH; ++k) {
        __syncthreads();   // previous k's readers done before overwrite
        const float4* Wg = (const float4*)(W + (size_t)k * F * F);
        float4* Ws = (float4*)Wk;
        for (int i = threadIdx.x; i < F * F / 4; i += 256) Ws[i] = Wg[i];
        __syncthreads();
        const int idx = arow[k];
        const float4* hr = (const float4*)(h + (size_t)idx * F);
#pragma unroll 2
        for (int f4 = 0; f4 < F / 4; ++f4) {
            float4 hv = hr[f4];
#pragma unroll
            for (int j = 0; j < 4; ++j) {
                float hf = (j == 0) ? hv.x : (j == 1) ? hv.y : (j == 2) ? hv.z : hv.w;
                const float4* wrow = (const float4*)(Wk + (f4 * 4 + j) * F);
#pragma unroll
                for (int o4 = 0; o4 < F / 4; ++o4) {
                    float4 w4 = wrow[o4];
                    acc[o4 * 4 + 0] = fmaf(hf, w4.x, acc[o4 * 4 + 0]);
                    acc[o4 * 4 + 1] = fmaf(hf, w4.y, acc[o4 * 4 + 1]);
                    acc[o4 * 4 + 2] = fmaf(hf, w4.z, acc[o4 * 4 + 2]);
                    acc[o4 * 4 + 3] = fmaf(hf, w4.w, acc[o4 * 4 + 3]);
                }
            }
        }
    }

    if (FINAL) {
        const float4* xr = (const float4*)(xres + (size_t)node * F);
#pragma unroll
        for (int o4 = 0; o4 < F / 4; ++o4) {
            float4 r = xr[o4];
            acc[o4 * 4 + 0] += r.x;
            acc[o4 * 4 + 1] += r.y;
            acc[o4 * 4 + 2] += r.z;
            acc[o4 * 4 + 3] += r.w;
        }
    } else {
        float mu = 0.f;
#pragma unroll
        for (int o = 0; o < F; ++o) mu += acc[o];
        mu *= (1.0f / F);
        float var = 0.f;
#pragma unroll
        for (int o = 0; o < F; ++o) { float d = acc[o] - mu; var += d * d; }
        float rstd = rsqrtf(var * (1.0f / F) + LN_EPS);
#pragma unroll
        for (int o = 0; o < F; ++o)
            acc[o] = silu_f((acc[o] - mu) * rstd * lnw[o] + lnb[o]);
    }

    float4* orow = (float4*)(out + (size_t)node * F);
#pragma unroll
    for (int o4 = 0; o4 < F / 4; ++o4) {
        float4 v;
        v.x = acc[o4 * 4 + 0]; v.y = acc[o4 * 4 + 1];
        v.z = acc[o4 * 4 + 2]; v.w = acc[o4 * 4 + 3];
        orow[o4] = v;
    }
}

extern "C" void kernel_launch(void* const* d_in, const int* in_sizes, int n_in,
                              void* d_out, int out_size, void* d_ws, size_t ws_size,
                              hipStream_t stream)
{
    const float* x    = (const float*)d_in[0];
    const int*   adjc = (const int*)d_in[1];
    const float* ln1w = (const float*)d_in[2];
    const float* ln1b = (const float*)d_in[3];
    const float* W1   = (const float*)d_in[4];
    const float* b1   = (const float*)d_in[5];
    const float* ln2w = (const float*)d_in[6];
    const float* ln2b = (const float*)d_in[7];
    const float* W2   = (const float*)d_in[8];
    const float* b2   = (const float*)d_in[9];
    float* out = (float*)d_out;

    float* h1 = (float*)d_ws;                       // N*F f32 = 50.3 MB
    float* h2 = h1 + (size_t)NNODES * F;            // N*F f32 = 50.3 MB

    ln1_silu_kernel<<<NNODES / 4, 256, 0, stream>>>(x, ln1w, ln1b, h1);
    gconv_kernel<0><<<NNODES / 256, 256, 0, stream>>>(h1, adjc, W1, b1, ln2w, ln2b, nullptr, h2);
    gconv_kernel<1><<<NNODES / 256, 256, 0, stream>>>(h2, adjc, W2, b2, nullptr, nullptr, x, out);
}

// Round 3
// 292.536 us; speedup vs baseline: 1.8989x; 1.8989x over previous
//
#include <hip/hip_runtime.h>

#define NNODES 196608
#define NH 9
#define F 64
#define K_TOT 576      // NH * F
#define KSTEPS 18      // K_TOT / 32
#define LN_EPS 1e-5f

typedef __attribute__((ext_vector_type(8))) short short8v;
typedef __attribute__((ext_vector_type(4))) float f32x4;

__device__ __forceinline__ unsigned short f2bf(float f) {
    unsigned int u = __float_as_uint(f);
    u += 0x7fff + ((u >> 16) & 1);          // round-to-nearest-even
    return (unsigned short)(u >> 16);
}
__device__ __forceinline__ float silu_f(float z) { return z / (1.0f + __expf(-z)); }

// Build bf16 transposed weights Wt[o][k] (k = head*64 + f) from f32 W[head][f][o].
__global__ __launch_bounds__(256) void prep_wt(const float* __restrict__ W1,
                                               const float* __restrict__ W2,
                                               unsigned short* __restrict__ Wt1,
                                               unsigned short* __restrict__ Wt2) {
    int tid = blockIdx.x * 256 + threadIdx.x;
    if (tid >= F * K_TOT) return;
    int k = tid % K_TOT, o = tid / K_TOT;
    Wt1[tid] = f2bf(W1[(size_t)k * F + o]);
    Wt2[tid] = f2bf(W2[(size_t)k * F + o]);
}

// LN + SiLU, f32 in -> bf16 out. 16 threads per row, float4 per thread.
__global__ __launch_bounds__(256) void ln1_silu(const float* __restrict__ x,
                                                const float* __restrict__ w,
                                                const float* __restrict__ b,
                                                unsigned short* __restrict__ out) {
    const int t = threadIdx.x;
    const int row = blockIdx.x * 16 + (t >> 4);
    const int fl = (t & 15) * 4;
    const float4 v = *(const float4*)(x + (size_t)row * F + fl);
    float s = v.x + v.y + v.z + v.w;
    float ss = v.x * v.x + v.y * v.y + v.z * v.z + v.w * v.w;
#pragma unroll
    for (int o = 8; o; o >>= 1) { s += __shfl_xor(s, o); ss += __shfl_xor(ss, o); }
    const float mu = s * (1.0f / F);
    const float rstd = rsqrtf(ss * (1.0f / F) - mu * mu + LN_EPS);
    const float4 wv = *(const float4*)(w + fl);
    const float4 bv = *(const float4*)(b + fl);
    ushort4 o4;
    o4.x = f2bf(silu_f((v.x - mu) * rstd * wv.x + bv.x));
    o4.y = f2bf(silu_f((v.y - mu) * rstd * wv.y + bv.y));
    o4.z = f2bf(silu_f((v.z - mu) * rstd * wv.z + bv.z));
    o4.w = f2bf(silu_f((v.w - mu) * rstd * wv.w + bv.w));
    *(ushort4*)(out + (size_t)row * F + fl) = o4;
}

// Gather + 9-head GEMM via MFMA. Block = 64 nodes, 4 waves (wave = o-tile of 16).
// A fragments loaded straight from global bf16 h (no LDS staging, no sync in loop).
// B fragments (Wt) held in 72 VGPRs per wave, loaded once.
// Epilogue transposes via LDS: FINAL==0 -> bias+LN2+SiLU -> bf16; FINAL==1 -> bias+residual -> f32.
template<int FINAL>
__global__ __launch_bounds__(256) void gconv_mfma(
    const unsigned short* __restrict__ h,
    const int* __restrict__ adjc,
    const unsigned short* __restrict__ Wt,
    const float* __restrict__ bias,
    const float* __restrict__ lnw, const float* __restrict__ lnb,
    const float* __restrict__ xres,
    void* __restrict__ outv)
{
    __shared__ float T[64][68];          // padded: 2-way bank conflicts only
    const int wave = threadIdx.x >> 6;
    const int lane = threadIdx.x & 63;
    const int l16 = lane & 15, lg = lane >> 4;
    const int nodeBase = blockIdx.x * 64;

    // B fragments: B[k][o], lane holds o = 16*wave + l16, k = 32*s + lg*8 + [0..7]
    short8v bfrag[KSTEPS];
    {
        const unsigned short* wr = Wt + (size_t)(wave * 16 + l16) * K_TOT + lg * 8;
#pragma unroll
        for (int s = 0; s < KSTEPS; ++s)
            bfrag[s] = *(const short8v*)(wr + s * 32);
    }

    f32x4 acc[4];
#pragma unroll
    for (int m = 0; m < 4; ++m) {
        acc[m] = (f32x4){0.f, 0.f, 0.f, 0.f};
        const int node = nodeBase + m * 16 + l16;
        const int* arow = adjc + (size_t)node * NH;
        int idx = 0;
#pragma unroll
        for (int s = 0; s < KSTEPS; ++s) {
            if ((s & 1) == 0) idx = arow[s >> 1];    // head = s/2
            // A[row=node(l16)][k=32s+lg*8+j] : 16B load from gathered bf16 row
            const short8v a = *(const short8v*)(h + (size_t)idx * F + (s & 1) * 32 + lg * 8);
            acc[m] = __builtin_amdgcn_mfma_f32_16x16x32_bf16(a, bfrag[s], acc[m], 0, 0, 0);
        }
    }

    // D layout: row(node) = m*16 + lg*4 + r, col(o) = wave*16 + l16
#pragma unroll
    for (int m = 0; m < 4; ++m)
#pragma unroll
        for (int r = 0; r < 4; ++r)
            T[m * 16 + lg * 4 + r][wave * 16 + l16] = acc[m][r];
    __syncthreads();

    const int t = threadIdx.x;
    const int nl = t >> 2, q = t & 3;                // 4 threads per node, 16 outputs each
    const int node = nodeBase + nl;
    float v[16];
#pragma unroll
    for (int i = 0; i < 16; ++i) v[i] = T[nl][q * 16 + i] + bias[q * 16 + i];

    if (FINAL) {
        float* out = (float*)outv;
#pragma unroll
        for (int i4 = 0; i4 < 4; ++i4) {
            const float4 xr = *(const float4*)(xres + (size_t)node * F + q * 16 + i4 * 4);
            float4 ov;
            ov.x = v[i4 * 4 + 0] + xr.x; ov.y = v[i4 * 4 + 1] + xr.y;
            ov.z = v[i4 * 4 + 2] + xr.z; ov.w = v[i4 * 4 + 3] + xr.w;
            *(float4*)(out + (size_t)node * F + q * 16 + i4 * 4) = ov;
        }
    } else {
        float s = 0.f, ss = 0.f;
#pragma unroll
        for (int i = 0; i < 16; ++i) { s += v[i]; ss += v[i] * v[i]; }
        s += __shfl_xor(s, 1); ss += __shfl_xor(ss, 1);
        s += __shfl_xor(s, 2); ss += __shfl_xor(ss, 2);
        const float mu = s * (1.0f / F);
        const float rstd = rsqrtf(ss * (1.0f / F) - mu * mu + LN_EPS);
        unsigned short* out = (unsigned short*)outv;
        unsigned short ob[16];
#pragma unroll
        for (int i = 0; i < 16; ++i) {
            const int o = q * 16 + i;
            const float y = (v[i] - mu) * rstd * lnw[o] + lnb[o];
            ob[i] = f2bf(silu_f(y));
        }
#pragma unroll
        for (int c = 0; c < 2; ++c)
            *(short8v*)(out + (size_t)node * F + q * 16 + c * 8) = *(short8v*)(ob + c * 8);
    }
}

extern "C" void kernel_launch(void* const* d_in, const int* in_sizes, int n_in,
                              void* d_out, int out_size, void* d_ws, size_t ws_size,
                              hipStream_t stream)
{
    const float* x    = (const float*)d_in[0];
    const int*   adjc = (const int*)d_in[1];
    const float* ln1w = (const float*)d_in[2];
    const float* ln1b = (const float*)d_in[3];
    const float* W1   = (const float*)d_in[4];
    const float* b1   = (const float*)d_in[5];
    const float* ln2w = (const float*)d_in[6];
    const float* ln2b = (const float*)d_in[7];
    const float* W2   = (const float*)d_in[8];
    const float* b2   = (const float*)d_in[9];
    float* out = (float*)d_out;

    unsigned short* h1  = (unsigned short*)d_ws;              // 25.2 MB bf16
    unsigned short* h2  = h1 + (size_t)NNODES * F;            // 25.2 MB bf16
    unsigned short* Wt1 = h2 + (size_t)NNODES * F;            // 144 KB
    unsigned short* Wt2 = Wt1 + F * K_TOT;                    // 144 KB

    prep_wt<<<(F * K_TOT + 255) / 256, 256, 0, stream>>>(W1, W2, Wt1, Wt2);
    ln1_silu<<<NNODES / 16, 256, 0, stream>>>(x, ln1w, ln1b, h1);
    gconv_mfma<0><<<NNODES / 64, 256, 0, stream>>>(h1, adjc, Wt1, b1, ln2w, ln2b, nullptr, h2);
    gconv_mfma<1><<<NNODES / 64, 256, 0, stream>>>(h2, adjc, Wt2, b2, nullptr, nullptr, x, out);
}

// Round 4
// 292.457 us; speedup vs baseline: 1.8994x; 1.0003x over previous
//
#include <hip/hip_runtime.h>

#define NNODES 196608
#define NH 9
#define F 64
#define K_TOT 576      // NH * F
#define KSTEPS 18      // K_TOT / 32
#define LN_EPS 1e-5f

typedef __attribute__((ext_vector_type(8))) short short8v;
typedef __attribute__((ext_vector_type(4))) float f32x4;

__device__ __forceinline__ unsigned short f2bf(float f) {
    unsigned int u = __float_as_uint(f);
    u += 0x7fff + ((u >> 16) & 1);          // round-to-nearest-even
    return (unsigned short)(u >> 16);
}
__device__ __forceinline__ float silu_f(float z) { return z / (1.0f + __expf(-z)); }

// Build bf16 transposed weights Wt[o][k] (k = head*64 + f) from f32 W[head][f][o].
__global__ __launch_bounds__(256) void prep_wt(const float* __restrict__ W1,
                                               const float* __restrict__ W2,
                                               unsigned short* __restrict__ Wt1,
                                               unsigned short* __restrict__ Wt2) {
    int tid = blockIdx.x * 256 + threadIdx.x;
    if (tid >= F * K_TOT) return;
    int k = tid % K_TOT, o = tid / K_TOT;
    Wt1[tid] = f2bf(W1[(size_t)k * F + o]);
    Wt2[tid] = f2bf(W2[(size_t)k * F + o]);
}

// LN + SiLU, f32 in -> bf16 out. 16 threads per row, float4 per thread.
__global__ __launch_bounds__(256) void ln1_silu(const float* __restrict__ x,
                                                const float* __restrict__ w,
                                                const float* __restrict__ b,
                                                unsigned short* __restrict__ out) {
    const int t = threadIdx.x;
    const int row = blockIdx.x * 16 + (t >> 4);
    const int fl = (t & 15) * 4;
    const float4 v = *(const float4*)(x + (size_t)row * F + fl);
    float s = v.x + v.y + v.z + v.w;
    float ss = v.x * v.x + v.y * v.y + v.z * v.z + v.w * v.w;
#pragma unroll
    for (int o = 8; o; o >>= 1) { s += __shfl_xor(s, o); ss += __shfl_xor(ss, o); }
    const float mu = s * (1.0f / F);
    const float rstd = rsqrtf(ss * (1.0f / F) - mu * mu + LN_EPS);
    const float4 wv = *(const float4*)(w + fl);
    const float4 bv = *(const float4*)(b + fl);
    ushort4 o4;
    o4.x = f2bf(silu_f((v.x - mu) * rstd * wv.x + bv.x));
    o4.y = f2bf(silu_f((v.y - mu) * rstd * wv.y + bv.y));
    o4.z = f2bf(silu_f((v.z - mu) * rstd * wv.z + bv.z));
    o4.w = f2bf(silu_f((v.w - mu) * rstd * wv.w + bv.w));
    *(ushort4*)(out + (size_t)row * F + fl) = o4;
}

// Gather + 9-head GEMM via MFMA. Block = 64 nodes, 4 waves (wave = o-tile of 16).
// __launch_bounds__(256,2): 256-VGPR budget so bfrag[18] (72 VGPR) stays resident
// (round-3 failure: default 8 waves/SIMD capped VGPR at 64 -> spills, FETCH +90MB).
// A-fragments double-buffered 9 at a time, software-pipelined over 8 half-m stages.
template<int FINAL>
__global__ __launch_bounds__(256, 2) void gconv_mfma(
    const unsigned short* __restrict__ h,
    const int* __restrict__ adjc,
    const unsigned short* __restrict__ Wt,
    const float* __restrict__ bias,
    const float* __restrict__ lnw, const float* __restrict__ lnb,
    const float* __restrict__ xres,
    void* __restrict__ outv)
{
    __shared__ float T[64][68];          // padded: 2-way bank conflicts only
    const int wave = threadIdx.x >> 6;
    const int lane = threadIdx.x & 63;
    const int l16 = lane & 15, lg = lane >> 4;
    const int nodeBase = blockIdx.x * 64;

    // All 36 gather indices up front (static indices only).
    int idx[4][9];
#pragma unroll
    for (int m = 0; m < 4; ++m) {
        const int* arow = adjc + (size_t)(nodeBase + m * 16 + l16) * NH;
#pragma unroll
        for (int hh = 0; hh < 9; ++hh) idx[m][hh] = arow[hh];
    }

    // B fragments resident: B[k][o], lane holds o = 16*wave + l16, k = 32*s + lg*8 + [0..7]
    short8v bfrag[KSTEPS];
    {
        const unsigned short* wr = Wt + (size_t)(wave * 16 + l16) * K_TOT + lg * 8;
#pragma unroll
        for (int s = 0; s < KSTEPS; ++s)
            bfrag[s] = *(const short8v*)(wr + s * 32);
    }

    f32x4 acc[4];
#pragma unroll
    for (int m = 0; m < 4; ++m) acc[m] = (f32x4){0.f, 0.f, 0.f, 0.f};

    short8v Ab0[9], Ab1[9];

#define ALOAD(BUF, M, HALF)                                                          \
    _Pragma("unroll")                                                                \
    for (int i = 0; i < 9; ++i) {                                                    \
        const int s = (HALF) * 9 + i;                                                \
        BUF[i] = *(const short8v*)(h + (size_t)idx[M][s >> 1] * F + (s & 1) * 32 + lg * 8); \
    }
#define AMFMA(BUF, M, HALF)                                                          \
    _Pragma("unroll")                                                                \
    for (int i = 0; i < 9; ++i) {                                                    \
        const int s = (HALF) * 9 + i;                                                \
        acc[M] = __builtin_amdgcn_mfma_f32_16x16x32_bf16(BUF[i], bfrag[s], acc[M], 0, 0, 0); \
    }

    ALOAD(Ab0, 0, 0);
    ALOAD(Ab1, 0, 1);
    AMFMA(Ab0, 0, 0);  ALOAD(Ab0, 1, 0);
    AMFMA(Ab1, 0, 1);  ALOAD(Ab1, 1, 1);
    AMFMA(Ab0, 1, 0);  ALOAD(Ab0, 2, 0);
    AMFMA(Ab1, 1, 1);  ALOAD(Ab1, 2, 1);
    AMFMA(Ab0, 2, 0);  ALOAD(Ab0, 3, 0);
    AMFMA(Ab1, 2, 1);  ALOAD(Ab1, 3, 1);
    AMFMA(Ab0, 3, 0);
    AMFMA(Ab1, 3, 1);
#undef ALOAD
#undef AMFMA

    // D layout: row(node) = m*16 + lg*4 + r, col(o) = wave*16 + l16
#pragma unroll
    for (int m = 0; m < 4; ++m)
#pragma unroll
        for (int r = 0; r < 4; ++r)
            T[m * 16 + lg * 4 + r][wave * 16 + l16] = acc[m][r];
    __syncthreads();

    const int t = threadIdx.x;
    const int nl = t >> 2, q = t & 3;                // 4 threads per node, 16 outputs each
    const int node = nodeBase + nl;
    float v[16];
#pragma unroll
    for (int i = 0; i < 16; ++i) v[i] = T[nl][q * 16 + i] + bias[q * 16 + i];

    if (FINAL) {
        float* out = (float*)outv;
#pragma unroll
        for (int i4 = 0; i4 < 4; ++i4) {
            const float4 xr = *(const float4*)(xres + (size_t)node * F + q * 16 + i4 * 4);
            float4 ov;
            ov.x = v[i4 * 4 + 0] + xr.x; ov.y = v[i4 * 4 + 1] + xr.y;
            ov.z = v[i4 * 4 + 2] + xr.z; ov.w = v[i4 * 4 + 3] + xr.w;
            *(float4*)(out + (size_t)node * F + q * 16 + i4 * 4) = ov;
        }
    } else {
        float s = 0.f, ss = 0.f;
#pragma unroll
        for (int i = 0; i < 16; ++i) { s += v[i]; ss += v[i] * v[i]; }
        s += __shfl_xor(s, 1); ss += __shfl_xor(ss, 1);
        s += __shfl_xor(s, 2); ss += __shfl_xor(ss, 2);
        const float mu = s * (1.0f / F);
        const float rstd = rsqrtf(ss * (1.0f / F) - mu * mu + LN_EPS);
        unsigned short* out = (unsigned short*)outv;
        unsigned short ob[16];
#pragma unroll
        for (int i = 0; i < 16; ++i) {
            const int o = q * 16 + i;
            const float y = (v[i] - mu) * rstd * lnw[o] + lnb[o];
            ob[i] = f2bf(silu_f(y));
        }
#pragma unroll
        for (int c = 0; c < 2; ++c)
            *(short8v*)(out + (size_t)node * F + q * 16 + c * 8) = *(short8v*)(ob + c * 8);
    }
}

extern "C" void kernel_launch(void* const* d_in, const int* in_sizes, int n_in,
                              void* d_out, int out_size, void* d_ws, size_t ws_size,
                              hipStream_t stream)
{
    const float* x    = (const float*)d_in[0];
    const int*   adjc = (const int*)d_in[1];
    const float* ln1w = (const float*)d_in[2];
    const float* ln1b = (const float*)d_in[3];
    const float* W1   = (const float*)d_in[4];
    const float* b1   = (const float*)d_in[5];
    const float* ln2w = (const float*)d_in[6];
    const float* ln2b = (const float*)d_in[7];
    const float* W2   = (const float*)d_in[8];
    const float* b2   = (const float*)d_in[9];
    float* out = (float*)d_out;

    unsigned short* h1  = (unsigned short*)d_ws;              // 25.2 MB bf16
    unsigned short* h2  = h1 + (size_t)NNODES * F;            // 25.2 MB bf16
    unsigned short* Wt1 = h2 + (size_t)NNODES * F;            // 144 KB
    unsigned short* Wt2 = Wt1 + F * K_TOT;                    // 144 KB

    prep_wt<<<(F * K_TOT + 255) / 256, 256, 0, stream>>>(W1, W2, Wt1, Wt2);
    ln1_silu<<<NNODES / 16, 256, 0, stream>>>(x, ln1w, ln1b, h1);
    gconv_mfma<0><<<NNODES / 64, 256, 0, stream>>>(h1, adjc, Wt1, b1, ln2w, ln2b, nullptr, h2);
    gconv_mfma<1><<<NNODES / 64, 256, 0, stream>>>(h2, adjc, Wt2, b2, nullptr, nullptr, x, out);
}

// Round 5
// 138.694 us; speedup vs baseline: 4.0052x; 2.1086x over previous
//
#include <hip/hip_runtime.h>

#define NNODES 196608
#define NH 9
#define F 64
#define K_TOT 576      // NH * F
#define KSTEPS 18      // K_TOT / 32
#define LN_EPS 1e-5f

typedef __attribute__((ext_vector_type(8))) short short8v;
typedef __attribute__((ext_vector_type(4))) float f32x4;

__device__ __forceinline__ unsigned short f2bf(float f) {
    unsigned int u = __float_as_uint(f);
    u += 0x7fff + ((u >> 16) & 1);          // round-to-nearest-even
    return (unsigned short)(u >> 16);
}
__device__ __forceinline__ float silu_f(float z) { return z / (1.0f + __expf(-z)); }

// Async global->LDS, 16 B per lane. Dest is wave-uniform base + lane*16 (linear).
__device__ __forceinline__ void gload_lds16(const void* g, void* l) {
    __builtin_amdgcn_global_load_lds((__attribute__((address_space(1))) void*)g,
                                     (__attribute__((address_space(3))) void*)l,
                                     16, 0, 0);
}

// Build bf16 transposed weights Wt[o][k] (k = head*64 + f) from f32 W[head][f][o].
__global__ __launch_bounds__(256) void prep_wt(const float* __restrict__ W1,
                                               const float* __restrict__ W2,
                                               unsigned short* __restrict__ Wt1,
                                               unsigned short* __restrict__ Wt2) {
    int tid = blockIdx.x * 256 + threadIdx.x;
    if (tid >= F * K_TOT) return;
    int k = tid % K_TOT, o = tid / K_TOT;
    Wt1[tid] = f2bf(W1[(size_t)k * F + o]);
    Wt2[tid] = f2bf(W2[(size_t)k * F + o]);
}

// LN + SiLU, f32 in -> bf16 out. 16 threads per row, float4 per thread.
__global__ __launch_bounds__(256) void ln1_silu(const float* __restrict__ x,
                                                const float* __restrict__ w,
                                                const float* __restrict__ b,
                                                unsigned short* __restrict__ out) {
    const int t = threadIdx.x;
    const int row = blockIdx.x * 16 + (t >> 4);
    const int fl = (t & 15) * 4;
    const float4 v = *(const float4*)(x + (size_t)row * F + fl);
    float s = v.x + v.y + v.z + v.w;
    float ss = v.x * v.x + v.y * v.y + v.z * v.z + v.w * v.w;
#pragma unroll
    for (int o = 8; o; o >>= 1) { s += __shfl_xor(s, o); ss += __shfl_xor(ss, o); }
    const float mu = s * (1.0f / F);
    const float rstd = rsqrtf(ss * (1.0f / F) - mu * mu + LN_EPS);
    const float4 wv = *(const float4*)(w + fl);
    const float4 bv = *(const float4*)(b + fl);
    ushort4 o4;
    o4.x = f2bf(silu_f((v.x - mu) * rstd * wv.x + bv.x));
    o4.y = f2bf(silu_f((v.y - mu) * rstd * wv.y + bv.y));
    o4.z = f2bf(silu_f((v.z - mu) * rstd * wv.z + bv.z));
    o4.w = f2bf(silu_f((v.w - mu) * rstd * wv.w + bv.w));
    *(ushort4*)(out + (size_t)row * F + fl) = o4;
}

// Block = 64 nodes, 4 waves. Per head hh: the 64 gathered rows (128 B each) are
// cooperatively staged ONCE into a double-buffered LDS tile via global_load_lds
// (round-4 lesson: 4 waves each re-gathering the same rows + compiler-sunk loads
// = serialized latency). LDS dest is linear (HW: base+lane*16); bank conflicts on
// the ds_read_b128 fragment reads are avoided by XOR-swizzling chunk^(row&7) on
// BOTH the per-lane global source and the read address (rule #21).
// amdgpu_waves_per_eu(3,3) pins the scheduler target so bfrag[18] stays resident
// (round-4: min-only bound let the scheduler remat everything down to 44 VGPR).
template<int FINAL>
__global__ __launch_bounds__(256) __attribute__((amdgpu_waves_per_eu(3, 3)))
void gconv_mfma(
    const unsigned short* __restrict__ h,
    const int* __restrict__ adjc,
    const unsigned short* __restrict__ Wt,
    const float* __restrict__ bias,
    const float* __restrict__ lnw, const float* __restrict__ lnb,
    const float* __restrict__ xres,
    void* __restrict__ outv)
{
    __shared__ __align__(16) char smem[64 * 68 * 4];   // 17408 B; tiles use first 16384
    unsigned short* tile = (unsigned short*)smem;       // [2][64][64] bf16
    float (*T)[68] = (float (*)[68])smem;               // epilogue reuse (after barrier)

    const int wave = threadIdx.x >> 6;
    const int lane = threadIdx.x & 63;
    const int l16 = lane & 15, lg = lane >> 4;
    const int nodeBase = blockIdx.x * 64;

    // Staging geometry: instr j (=2w, 2w+1) covers rows 8j..8j+7, 8 chunks of 16 B.
    const int srow = lane >> 3;              // row within group of 8 (== row&7)
    const int sswz = (lane & 7) ^ srow;      // pre-swizzled global chunk for this lane
    const int rA = wave * 16 + srow;
    const int rB = rA + 8;

    int idxA[NH], idxB[NH];
    {
        const int* a0 = adjc + (size_t)(nodeBase + rA) * NH;
        const int* a1 = adjc + (size_t)(nodeBase + rB) * NH;
#pragma unroll
        for (int hh = 0; hh < NH; ++hh) { idxA[hh] = a0[hh]; idxB[hh] = a1[hh]; }
    }

    // B fragments resident: lane holds o = 16*wave + l16, k = 32*s + lg*8 + [0..7]
    short8v bfrag[KSTEPS];
    {
        const unsigned short* wr = Wt + (size_t)(wave * 16 + l16) * K_TOT + lg * 8;
#pragma unroll
        for (int s = 0; s < KSTEPS; ++s) bfrag[s] = *(const short8v*)(wr + s * 32);
    }

    f32x4 acc[4];
#pragma unroll
    for (int m = 0; m < 4; ++m) acc[m] = (f32x4){0.f, 0.f, 0.f, 0.f};

#define STAGE(BUF, HH)                                                         \
    do {                                                                       \
        gload_lds16(h + (size_t)idxA[HH] * F + sswz * 8,                       \
                    (char*)tile + (BUF) * 8192 + (2 * wave) * 1024);           \
        gload_lds16(h + (size_t)idxB[HH] * F + sswz * 8,                       \
                    (char*)tile + (BUF) * 8192 + (2 * wave + 1) * 1024);       \
    } while (0)

#define COMPUTE(BUF, HH)                                                       \
    _Pragma("unroll")                                                          \
    for (int m = 0; m < 4; ++m) {                                              \
        _Pragma("unroll")                                                      \
        for (int kh = 0; kh < 2; ++kh) {                                       \
            const short8v a = *(const short8v*)((char*)tile + (BUF) * 8192     \
                + (m * 16 + l16) * 128 + (((kh * 4 + lg) ^ (l16 & 7)) * 16));  \
            acc[m] = __builtin_amdgcn_mfma_f32_16x16x32_bf16(                  \
                a, bfrag[(HH) * 2 + kh], acc[m], 0, 0, 0);                     \
        }                                                                      \
    }

    STAGE(0, 0);
    __syncthreads();
#pragma unroll
    for (int hh = 0; hh < NH; ++hh) {
        if (hh < NH - 1) STAGE((hh + 1) & 1, hh + 1);   // issue next head first
        COMPUTE(hh & 1, hh);                            // overlap with in-flight stage
        __syncthreads();                                // drain + swap
    }
#undef STAGE
#undef COMPUTE

    // Epilogue: transpose via LDS (reuses tile region; last barrier above covers it).
    // D layout: row(node) = m*16 + lg*4 + r, col(o) = wave*16 + l16
#pragma unroll
    for (int m = 0; m < 4; ++m)
#pragma unroll
        for (int r = 0; r < 4; ++r)
            T[m * 16 + lg * 4 + r][wave * 16 + l16] = acc[m][r];
    __syncthreads();

    const int t = threadIdx.x;
    const int nl = t >> 2, q = t & 3;                // 4 threads per node, 16 outputs each
    const int node = nodeBase + nl;
    float v[16];
#pragma unroll
    for (int i = 0; i < 16; ++i) v[i] = T[nl][q * 16 + i] + bias[q * 16 + i];

    if (FINAL) {
        float* out = (float*)outv;
#pragma unroll
        for (int i4 = 0; i4 < 4; ++i4) {
            const float4 xr = *(const float4*)(xres + (size_t)node * F + q * 16 + i4 * 4);
            float4 ov;
            ov.x = v[i4 * 4 + 0] + xr.x; ov.y = v[i4 * 4 + 1] + xr.y;
            ov.z = v[i4 * 4 + 2] + xr.z; ov.w = v[i4 * 4 + 3] + xr.w;
            *(float4*)(out + (size_t)node * F + q * 16 + i4 * 4) = ov;
        }
    } else {
        float s = 0.f, ss = 0.f;
#pragma unroll
        for (int i = 0; i < 16; ++i) { s += v[i]; ss += v[i] * v[i]; }
        s += __shfl_xor(s, 1); ss += __shfl_xor(ss, 1);
        s += __shfl_xor(s, 2); ss += __shfl_xor(ss, 2);
        const float mu = s * (1.0f / F);
        const float rstd = rsqrtf(ss * (1.0f / F) - mu * mu + LN_EPS);
        unsigned short* out = (unsigned short*)outv;
        unsigned short ob[16];
#pragma unroll
        for (int i = 0; i < 16; ++i) {
            const int o = q * 16 + i;
            const float y = (v[i] - mu) * rstd * lnw[o] + lnb[o];
            ob[i] = f2bf(silu_f(y));
        }
#pragma unroll
        for (int c = 0; c < 2; ++c)
            *(short8v*)(out + (size_t)node * F + q * 16 + c * 8) = *(short8v*)(ob + c * 8);
    }
}

extern "C" void kernel_launch(void* const* d_in, const int* in_sizes, int n_in,
                              void* d_out, int out_size, void* d_ws, size_t ws_size,
                              hipStream_t stream)
{
    const float* x    = (const float*)d_in[0];
    const int*   adjc = (const int*)d_in[1];
    const float* ln1w = (const float*)d_in[2];
    const float* ln1b = (const float*)d_in[3];
    const float* W1   = (const float*)d_in[4];
    const float* b1   = (const float*)d_in[5];
    const float* ln2w = (const float*)d_in[6];
    const float* ln2b = (const float*)d_in[7];
    const float* W2   = (const float*)d_in[8];
    const float* b2   = (const float*)d_in[9];
    float* out = (float*)d_out;

    unsigned short* h1  = (unsigned short*)d_ws;              // 25.2 MB bf16
    unsigned short* h2  = h1 + (size_t)NNODES * F;            // 25.2 MB bf16
    unsigned short* Wt1 = h2 + (size_t)NNODES * F;            // 144 KB
    unsigned short* Wt2 = Wt1 + F * K_TOT;                    // 144 KB

    prep_wt<<<(F * K_TOT + 255) / 256, 256, 0, stream>>>(W1, W2, Wt1, Wt2);
    ln1_silu<<<NNODES / 16, 256, 0, stream>>>(x, ln1w, ln1b, h1);
    gconv_mfma<0><<<NNODES / 64, 256, 0, stream>>>(h1, adjc, Wt1, b1, ln2w, ln2b, nullptr, h2);
    gconv_mfma<1><<<NNODES / 64, 256, 0, stream>>>(h2, adjc, Wt2, b2, nullptr, nullptr, x, out);
}